// Round 11
// baseline (76.327 us; speedup 1.0000x reference)
//
#include <hip/hip_runtime.h>
#include <cmath>

// Problem geometry (fixed: im is (1, 4096, 4096, 3) f32 NHWC)
constexpr int H    = 4096;
constexpr int W    = 4096;
constexpr int C    = 3;
constexpr int WF   = W * C;    // 12288 floats per image row
constexpr int BT   = 128;      // threads per block (2 waves: min retire-skew)
constexpr int TW   = BT * 4;   // 512 floats per block
constexpr int RPT  = 8;        // output rows per block

typedef float f32x4 __attribute__((ext_vector_type(4)));  // nt-store friendly

// sqrt(v + 0.375); the Anscombe 2x is folded into the horizontal weights.
__device__ __forceinline__ float sq1(float v) {
    return __builtin_amdgcn_sqrtf(v + 0.375f);
}
__device__ __forceinline__ float4 sq4(float4 v) {
    return make_float4(sq1(v.x), sq1(v.y), sq1(v.z), sq1(v.w));
}

// Fused Anscombe -> separable 3x3 Gaussian (zero pad) -> clip -> inverse
// Anscombe. One float4 per thread per row: every wave-wide load AND store
// instruction spans a contiguous 1KB block (sector-complete -> NT streams
// with zero write amplification, verified R10: WRITE_SIZE exact). NT stores
// keep L2/L3 for the read stream. 2-wave blocks: halves the block-retire
// skew bubble that capped occupancy at 76% with 4-wave blocks (R10); 16
// wg/CU x 128 thr = 2048 = full residency possible. No LDS, no barriers,
// no cross-lane ops; rolling vertical window, depth-1 prefetch.
// R6 lesson: never force min-waves above live-state needs (spill disaster).
// R9 lesson: stores must be lane-contiguous per instruction (or they RMW
// partial 64B sectors and serialize with the read stream).
__global__ __launch_bounds__(BT, 4) void anscombe_gauss_kernel(
    const float* __restrict__ in, float* __restrict__ out,
    float wa2, float wb2, float wa, float wb, float c1, float c3)
{
    const int tid = threadIdx.x;
    const int gc  = blockIdx.x * TW + tid * 4;   // this thread's float4 column
    const int h0  = blockIdx.y * RPT;

    // Row-edge lanes (2 in the whole grid): clamp address, fill after load.
    const bool okL = (gc >= 4);
    const bool okR = (gc + 8 <= WF);
    const int offL = okL ? gc - 4 : gc;
    const int offR = okR ? gc + 4 : gc;

    const float4 cfill = make_float4(-0.375f, -0.375f, -0.375f, -0.375f);

    auto loadrow = [&](int h, float4& c, float4& l, float4& r) {
        if ((unsigned)h < (unsigned)H) {
            const float* rp = in + (long)h * WF;
            c = *(const float4*)(rp + gc);
            l = *(const float4*)(rp + offL);
            r = *(const float4*)(rp + offR);
            if (!okL) l = cfill;
            if (!okR) r = cfill;
        } else {
            c = l = r = cfill;           // OOB row: sqrt(0) == 0 == zero pad
        }
    };

    float4 pc, pl, pr;
    loadrow(h0 - 1, pc, pl, pr);

    float hp[4] = {0, 0, 0, 0};
    float hc[4] = {0, 0, 0, 0};

    #pragma unroll
    for (int s = 0; s < RPT + 2; ++s) {
        const float4 vc = pc, vl = pl, vr = pr;
        if (s < RPT + 1) loadrow(h0 + s, pc, pl, pr);   // prefetch next row

        const float4 a  = sq4(vc);
        const float4 aL = sq4(vl);
        const float4 aR = sq4(vr);

        float hn[4];
        hn[0] = wa2 * (aL.y + a.w)  + wb2 * a.x;
        hn[1] = wa2 * (aL.z + aR.x) + wb2 * a.y;
        hn[2] = wa2 * (aL.w + aR.y) + wb2 * a.z;
        hn[3] = wa2 * (a.x  + aR.z) + wb2 * a.w;

        if (s >= 2) {
            const int ho = h0 + s - 2;
            float o[4];
            #pragma unroll
            for (int j = 0; j < 4; ++j) {
                float y = wa * (hp[j] + hn[j]) + wb * hc[j];
                y = __builtin_amdgcn_fmed3f(y, 0.0f, 255.0f);  // 1-op clamp
                // y >= ~0.17 always (center tap always in-image): rcp safe
                float ry = __builtin_amdgcn_rcpf(y);
                o[j] = fmaf(0.25f * y, y,
                        fmaf(ry, fmaf(ry, fmaf(ry, c3, -1.375f), c1), -0.125f));
            }
            f32x4 ov = {o[0], o[1], o[2], o[3]};
            __builtin_nontemporal_store(ov, (f32x4*)(out + (long)ho * WF + gc));
        }
        #pragma unroll
        for (int j = 0; j < 4; ++j) { hp[j] = hc[j]; hc[j] = hn[j]; }
    }
}

extern "C" void kernel_launch(void* const* d_in, const int* in_sizes, int n_in,
                              void* d_out, int out_size, void* d_ws, size_t ws_size,
                              hipStream_t stream) {
    const float* in = (const float*)d_in[0];
    float* out      = (float*)d_out;

    // Separable Gaussian weights (double precision on host).
    // 2D normalized kernel == outer([a,b,a],[a,b,a]) with a+b+a == 1.
    const double sig2x2 = 2.0 * 1.3 * 1.3;
    const double e1     = std::exp(-1.0 / sig2x2);
    const double inv1d  = 1.0 / (1.0 + 2.0 * e1);
    const float  wa     = (float)(e1 * inv1d);
    const float  wb     = (float)inv1d;
    const float  wa2    = (float)(2.0 * e1 * inv1d);   // Anscombe 2x folded in
    const float  wb2    = (float)(2.0 * inv1d);

    const double s  = std::sqrt(1.5);
    const float  c1 = (float)(0.25  * s);
    const float  c3 = (float)(0.625 * s);

    dim3 grid(WF / TW, H / RPT);   // 24 x 512 = 12288 blocks (2 waves each)
    anscombe_gauss_kernel<<<grid, BT, 0, stream>>>(in, out, wa2, wb2, wa, wb, c1, c3);
}

// Round 12
// 73.103 us; speedup vs baseline: 1.0441x; 1.0441x over previous
//
#include <hip/hip_runtime.h>
#include <cmath>

// Problem geometry (fixed: im is (1, 4096, 4096, 3) f32 NHWC)
constexpr int H    = 4096;
constexpr int W    = 4096;
constexpr int C    = 3;
constexpr int WF   = W * C;    // 12288 floats per image row
constexpr int BT   = 512;      // threads per block (8 waves: amortize per-block
                               // fixed cost; R10/R11 showed bigger blocks win)
constexpr int TW   = BT * 4;   // 2048 floats per block
constexpr int RPT  = 8;        // output rows per block

typedef float f32x4 __attribute__((ext_vector_type(4)));  // nt-store friendly

// sqrt(v + 0.375); the Anscombe 2x is folded into the horizontal weights.
__device__ __forceinline__ float sq1(float v) {
    return __builtin_amdgcn_sqrtf(v + 0.375f);
}
__device__ __forceinline__ float4 sq4(float4 v) {
    return make_float4(sq1(v.x), sq1(v.y), sq1(v.z), sq1(v.w));
}

// Fused Anscombe -> separable 3x3 Gaussian (zero pad) -> clip -> inverse
// Anscombe. One float4 per thread per row: every wave-wide load AND store
// instruction spans a contiguous 1KB block (sector-complete -> NT streams
// with zero write amplification; WRITE_SIZE exact, verified R10/R11).
// NT stores keep L2/L3 for the read stream. Block-size ladder measured:
// 128thr=76.3us, 256thr=73.2us (same total waves) -> per-block fixed costs
// (dispatch + 2 warm-up stages) dominate the residual; 512thr halves them
// again. No LDS, no barriers, no cross-lane ops; rolling vertical window,
// depth-1 prefetch (compiler pipelines the fully-unrolled stage loop).
// R6 lesson: never force min-waves above live-state needs (spill disaster).
// R9 lesson: stores must be lane-contiguous per instruction (or they RMW
// partial 64B sectors and serialize with the read stream).
__global__ __launch_bounds__(BT, 4) void anscombe_gauss_kernel(
    const float* __restrict__ in, float* __restrict__ out,
    float wa2, float wb2, float wa, float wb, float c1, float c3)
{
    const int tid = threadIdx.x;
    const int gc  = blockIdx.x * TW + tid * 4;   // this thread's float4 column
    const int h0  = blockIdx.y * RPT;

    // Row-edge lanes (2 in the whole grid): clamp address, fill after load.
    const bool okL = (gc >= 4);
    const bool okR = (gc + 8 <= WF);
    const int offL = okL ? gc - 4 : gc;
    const int offR = okR ? gc + 4 : gc;

    const float4 cfill = make_float4(-0.375f, -0.375f, -0.375f, -0.375f);

    auto loadrow = [&](int h, float4& c, float4& l, float4& r) {
        if ((unsigned)h < (unsigned)H) {
            const float* rp = in + (long)h * WF;
            c = *(const float4*)(rp + gc);
            l = *(const float4*)(rp + offL);
            r = *(const float4*)(rp + offR);
            if (!okL) l = cfill;
            if (!okR) r = cfill;
        } else {
            c = l = r = cfill;           // OOB row: sqrt(0) == 0 == zero pad
        }
    };

    float4 pc, pl, pr;
    loadrow(h0 - 1, pc, pl, pr);

    float hp[4] = {0, 0, 0, 0};
    float hc[4] = {0, 0, 0, 0};

    #pragma unroll
    for (int s = 0; s < RPT + 2; ++s) {
        const float4 vc = pc, vl = pl, vr = pr;
        if (s < RPT + 1) loadrow(h0 + s, pc, pl, pr);   // prefetch next row

        const float4 a  = sq4(vc);
        const float4 aL = sq4(vl);
        const float4 aR = sq4(vr);

        float hn[4];
        hn[0] = wa2 * (aL.y + a.w)  + wb2 * a.x;
        hn[1] = wa2 * (aL.z + aR.x) + wb2 * a.y;
        hn[2] = wa2 * (aL.w + aR.y) + wb2 * a.z;
        hn[3] = wa2 * (a.x  + aR.z) + wb2 * a.w;

        if (s >= 2) {
            const int ho = h0 + s - 2;
            float o[4];
            #pragma unroll
            for (int j = 0; j < 4; ++j) {
                float y = wa * (hp[j] + hn[j]) + wb * hc[j];
                y = __builtin_amdgcn_fmed3f(y, 0.0f, 255.0f);  // 1-op clamp
                // y >= ~0.17 always (center tap always in-image): rcp safe
                float ry = __builtin_amdgcn_rcpf(y);
                o[j] = fmaf(0.25f * y, y,
                        fmaf(ry, fmaf(ry, fmaf(ry, c3, -1.375f), c1), -0.125f));
            }
            f32x4 ov = {o[0], o[1], o[2], o[3]};
            __builtin_nontemporal_store(ov, (f32x4*)(out + (long)ho * WF + gc));
        }
        #pragma unroll
        for (int j = 0; j < 4; ++j) { hp[j] = hc[j]; hc[j] = hn[j]; }
    }
}

extern "C" void kernel_launch(void* const* d_in, const int* in_sizes, int n_in,
                              void* d_out, int out_size, void* d_ws, size_t ws_size,
                              hipStream_t stream) {
    const float* in = (const float*)d_in[0];
    float* out      = (float*)d_out;

    // Separable Gaussian weights (double precision on host).
    // 2D normalized kernel == outer([a,b,a],[a,b,a]) with a+b+a == 1.
    const double sig2x2 = 2.0 * 1.3 * 1.3;
    const double e1     = std::exp(-1.0 / sig2x2);
    const double inv1d  = 1.0 / (1.0 + 2.0 * e1);
    const float  wa     = (float)(e1 * inv1d);
    const float  wb     = (float)inv1d;
    const float  wa2    = (float)(2.0 * e1 * inv1d);   // Anscombe 2x folded in
    const float  wb2    = (float)(2.0 * inv1d);

    const double s  = std::sqrt(1.5);
    const float  c1 = (float)(0.25  * s);
    const float  c3 = (float)(0.625 * s);

    dim3 grid(WF / TW, H / RPT);   // 6 x 512 = 3072 blocks (8 waves each)
    anscombe_gauss_kernel<<<grid, BT, 0, stream>>>(in, out, wa2, wb2, wa, wb, c1, c3);
}

// Round 13
// 72.013 us; speedup vs baseline: 1.0599x; 1.0151x over previous
//
#include <hip/hip_runtime.h>
#include <cmath>

// Problem geometry (fixed: im is (1, 4096, 4096, 3) f32 NHWC)
constexpr int H    = 4096;
constexpr int W    = 4096;
constexpr int C    = 3;
constexpr int WF   = W * C;      // 12288 floats per image row
constexpr int BT   = 256;        // threads per block
constexpr int TW   = 2048;       // floats per block (two 1024-float halves)
constexpr int HALF = 1024;
constexpr int RPT  = 8;          // output rows per block

typedef float f32x4 __attribute__((ext_vector_type(4)));  // nt-store friendly

// sqrt(v + 0.375); the Anscombe 2x is folded into the horizontal weights.
__device__ __forceinline__ float sq1(float v) {
    return __builtin_amdgcn_sqrtf(v + 0.375f);
}
__device__ __forceinline__ float4 sq4(float4 v) {
    return make_float4(sq1(v.x), sq1(v.y), sq1(v.z), sq1(v.w));
}

// Fused Anscombe -> separable 3x3 Gaussian (zero pad) -> clip -> inverse
// Anscombe. SPLIT-TILE EPT=8: each thread owns float4 p (lower half) and
// q = p+1024 (upper half) of a 2048-float tile, so every wave-wide load AND
// store instruction spans a contiguous 1KB block (sector-complete -> NT
// streams, zero write amplification). vs EPT=4 this doubles per-wave
// in-flight loads (6/stage) and gives 2 independent ILP chains -- the MLP
// that covers HBM/L2 latency (R10-R12 plateaued at 73us with occupancy~70%,
// VALUBusy 30%, BW 72% of ceiling: latency-coverage-bound, not pipe-bound).
// R6 note: this layout previously spilled ONLY because launch_bounds(256,8)
// forced VGPR=32; live state ~56 VGPR fits the (256,4) budget at <=64 VGPR
// -> still 8 waves/SIMD residency. No LDS, no barriers, no cross-lane ops.
// R9 lesson: stores must be lane-contiguous per instruction.
__global__ __launch_bounds__(BT, 4) void anscombe_gauss_kernel(
    const float* __restrict__ in, float* __restrict__ out,
    float wa2, float wb2, float wa, float wb, float c1, float c3)
{
    const int tid = threadIdx.x;
    const int p   = blockIdx.x * TW + tid * 4;   // lower-half float4
    const int q   = p + HALF;                    // upper-half float4
    const int h0  = blockIdx.y * RPT;

    // Row-edge lanes: lower-left halo OOB only at (bx=0,tid=0); upper-right
    // halo OOB only at (bx=last,tid=255). q-4 >= 1020 always in-row.
    const bool okL = (p >= 4);
    const bool okR = (q + 8 <= WF);
    const int offL = okL ? p - 4 : p;
    const int offR = okR ? q + 4 : q;

    const float4 cfill = make_float4(-0.375f, -0.375f, -0.375f, -0.375f);

    auto loadrow = [&](int h, float4& c0, float4& l0, float4& r0,
                               float4& c1v, float4& l1, float4& r1) {
        if ((unsigned)h < (unsigned)H) {
            const float* rp = in + (long)h * WF;
            c0  = *(const float4*)(rp + p);
            l0  = *(const float4*)(rp + offL);
            r0  = *(const float4*)(rp + p + 4);   // in-row: p+8 <= WF always
            c1v = *(const float4*)(rp + q);
            l1  = *(const float4*)(rp + q - 4);   // in-row: q >= 1024
            r1  = *(const float4*)(rp + offR);
            if (!okL) l0 = cfill;                 // 1 lane in grid
            if (!okR) r1 = cfill;                 // 1 lane in grid
        } else {
            c0 = l0 = r0 = c1v = l1 = r1 = cfill; // OOB row: sqrt(0)==0==pad
        }
    };

    float4 pc0, pl0, pr0, pc1, pl1, pr1;
    loadrow(h0 - 1, pc0, pl0, pr0, pc1, pl1, pr1);

    float hp[8] = {0,0,0,0,0,0,0,0};
    float hc[8] = {0,0,0,0,0,0,0,0};

    #pragma unroll
    for (int s = 0; s < RPT + 2; ++s) {
        const float4 vc0 = pc0, vl0 = pl0, vr0 = pr0;
        const float4 vc1 = pc1, vl1 = pl1, vr1 = pr1;
        if (s < RPT + 1) loadrow(h0 + s, pc0, pl0, pr0, pc1, pl1, pr1);

        const float4 a0 = sq4(vc0), aL0 = sq4(vl0), aR0 = sq4(vr0);
        const float4 a1 = sq4(vc1), aL1 = sq4(vl1), aR1 = sq4(vr1);

        float hn[8];
        hn[0] = wa2 * (aL0.y + a0.w)  + wb2 * a0.x;
        hn[1] = wa2 * (aL0.z + aR0.x) + wb2 * a0.y;
        hn[2] = wa2 * (aL0.w + aR0.y) + wb2 * a0.z;
        hn[3] = wa2 * (a0.x  + aR0.z) + wb2 * a0.w;
        hn[4] = wa2 * (aL1.y + a1.w)  + wb2 * a1.x;
        hn[5] = wa2 * (aL1.z + aR1.x) + wb2 * a1.y;
        hn[6] = wa2 * (aL1.w + aR1.y) + wb2 * a1.z;
        hn[7] = wa2 * (a1.x  + aR1.z) + wb2 * a1.w;

        if (s >= 2) {
            const int ho = h0 + s - 2;
            float o[8];
            #pragma unroll
            for (int j = 0; j < 8; ++j) {
                float y = wa * (hp[j] + hn[j]) + wb * hc[j];
                y = __builtin_amdgcn_fmed3f(y, 0.0f, 255.0f);  // 1-op clamp
                // y >= ~0.17 always (center tap always in-image): rcp safe
                float ry = __builtin_amdgcn_rcpf(y);
                o[j] = fmaf(0.25f * y, y,
                        fmaf(ry, fmaf(ry, fmaf(ry, c3, -1.375f), c1), -0.125f));
            }
            float* op = out + (long)ho * WF;
            f32x4 o0 = {o[0], o[1], o[2], o[3]};
            f32x4 o1 = {o[4], o[5], o[6], o[7]};
            __builtin_nontemporal_store(o0, (f32x4*)(op + p));
            __builtin_nontemporal_store(o1, (f32x4*)(op + q));
        }
        #pragma unroll
        for (int j = 0; j < 8; ++j) { hp[j] = hc[j]; hc[j] = hn[j]; }
    }
}

extern "C" void kernel_launch(void* const* d_in, const int* in_sizes, int n_in,
                              void* d_out, int out_size, void* d_ws, size_t ws_size,
                              hipStream_t stream) {
    const float* in = (const float*)d_in[0];
    float* out      = (float*)d_out;

    // Separable Gaussian weights (double precision on host).
    // 2D normalized kernel == outer([a,b,a],[a,b,a]) with a+b+a == 1.
    const double sig2x2 = 2.0 * 1.3 * 1.3;
    const double e1     = std::exp(-1.0 / sig2x2);
    const double inv1d  = 1.0 / (1.0 + 2.0 * e1);
    const float  wa     = (float)(e1 * inv1d);
    const float  wb     = (float)inv1d;
    const float  wa2    = (float)(2.0 * e1 * inv1d);   // Anscombe 2x folded in
    const float  wb2    = (float)(2.0 * inv1d);

    const double s  = std::sqrt(1.5);
    const float  c1 = (float)(0.25  * s);
    const float  c3 = (float)(0.625 * s);

    dim3 grid(WF / TW, H / RPT);   // 6 x 512 = 3072 blocks (4 waves each)
    anscombe_gauss_kernel<<<grid, BT, 0, stream>>>(in, out, wa2, wb2, wa, wb, c1, c3);
}